// Round 9
// baseline (1483.831 us; speedup 1.0000x reference)
//
#include <hip/hip_runtime.h>

#define NROWS 100000
#define C_IN 16
#define C_OUT 32
#define KK 27
#define EPS 1e-5f
#define SLOPE 0.01f

#define NC (NROWS * C_OUT)   // 3,200,000 floats per [N,32] buffer

// stats layout (floats): sum1, sq1, sumR, sqR, sum2, sq2 (32 each)
#define ST_SUM1 0
#define ST_SQ1  32
#define ST_SUMR 64
#define ST_SQR  96
#define ST_SUM2 128
#define ST_SQ2  160

typedef unsigned short u16;

__device__ __forceinline__ unsigned bf16rne(float x) {
  unsigned u = __float_as_uint(x);
  return (u + 0x7fffu + ((u >> 16) & 1u)) >> 16;
}
__device__ __forceinline__ unsigned pack2(float lo, float hi) {
  return bf16rne(lo) | (bf16rne(hi) << 16);
}
__device__ __forceinline__ float blo(unsigned p) { return __uint_as_float(p << 16); }
__device__ __forceinline__ float bhi(unsigned p) { return __uint_as_float(p & 0xffff0000u); }

// ---------------- mask dtype detection: bool(u8) vs int32 ----------------
__global__ __launch_bounds__(256) void k_detect(const unsigned char* __restrict__ mb,
                                                int* __restrict__ flag) {
  __shared__ int found;
  if (threadIdx.x == 0) found = 0;
  __syncthreads();
  int f = 0;
  for (int i = threadIdx.x; i < 4096; i += 256)
    if ((i & 3) != 0 && mb[i] != 0) f = 1;
  if (f) atomicOr(&found, 1);
  __syncthreads();
  if (threadIdx.x == 0) *flag = found;  // 1 => u8 layout, 0 => int32 layout
}

// ---------------- canon: pack mask bits, bf16 feature table, transpose neighbors --------
__global__ __launch_bounds__(256) void k_canon(
    const void* __restrict__ mask, const int* __restrict__ flag,
    const int* __restrict__ neighbors, const float* __restrict__ features,
    unsigned* __restrict__ umask, u16* __restrict__ featb, int* __restrict__ nbT) {
  const int n = blockIdx.x * 256 + threadIdx.x;
  if (n >= NROWS) return;
  unsigned bits = 0;
  if (*flag) {
    const unsigned char* m = (const unsigned char*)mask + (size_t)n * KK;
#pragma unroll
    for (int k = 0; k < KK; ++k) bits |= (unsigned)(m[k] != 0) << k;
  } else {
    const int* m = (const int*)mask + (size_t)n * KK;
#pragma unroll
    for (int k = 0; k < KK; ++k) bits |= (unsigned)(m[k] != 0) << k;
  }
  umask[n] = bits;

  const int* nb = neighbors + (size_t)n * KK;
#pragma unroll
  for (int k = 0; k < KK; ++k) nbT[(size_t)k * NROWS + n] = nb[k];

  const float4* fp = reinterpret_cast<const float4*>(features + (size_t)n * C_IN);
  float f[C_IN];
#pragma unroll
  for (int j = 0; j < C_IN / 4; ++j) {
    float4 v = fp[j];
    f[4 * j] = v.x; f[4 * j + 1] = v.y; f[4 * j + 2] = v.z; f[4 * j + 3] = v.w;
  }
  uint4 r0, r1;
  r0.x = pack2(f[0], f[1]);  r0.y = pack2(f[2], f[3]);
  r0.z = pack2(f[4], f[5]);  r0.w = pack2(f[6], f[7]);
  r1.x = pack2(f[8], f[9]);  r1.y = pack2(f[10], f[11]);
  r1.z = pack2(f[12], f[13]); r1.w = pack2(f[14], f[15]);
  uint4* fb = reinterpret_cast<uint4*>(featb + (size_t)n * C_IN);
  fb[0] = r0; fb[1] = r1;
}

// ---------------- conv1: LDS-staged weights + pipelined bf16 gathers + residual + stats --
// block 256 = 4 waves; wave w: rows [bid*64 .. +63], out-channels [w*8 .. w*8+7]
__global__ __launch_bounds__(256, 4) void k_conv1(
    const float* __restrict__ features, const u16* __restrict__ featb,
    const int* __restrict__ nbT, const unsigned* __restrict__ umask,
    const float* __restrict__ W1, const float* __restrict__ Win,
    float* __restrict__ y1, float* __restrict__ rbuf, float* __restrict__ stats) {
  __shared__ float sW[2][C_IN * C_OUT];   // 2 x 2 KB double buffer
  __shared__ float sWin[C_IN * C_OUT];    // 2 KB
  const int tid = threadIdx.x;
  const int lane = tid & 63;
  const int d0 = (tid >> 6) * 8;          // wave-uniform
  const int row = blockIdx.x * 64 + lane;
  const bool valid = row < NROWS;
  const unsigned um = valid ? umask[row] : 0u;

  // stage Win and W1[k=0] (512 floats each; 128 threads x float4)
  if (tid < 128) {
    reinterpret_cast<float4*>(sWin)[tid] = reinterpret_cast<const float4*>(Win)[tid];
    reinterpret_cast<float4*>(sW[0])[tid] = reinterpret_cast<const float4*>(W1)[tid];
  }

  // prefetch gather for k=0
  int idx0 = valid ? nbT[row] : 0;
  const uint4* g0 = reinterpret_cast<const uint4*>(featb + (size_t)idx0 * C_IN);
  uint4 q0 = g0[0], q1 = g0[1];

  // row's own features (residual input)
  float f[C_IN];
  if (valid) {
    const float4* fp = reinterpret_cast<const float4*>(features + (size_t)row * C_IN);
#pragma unroll
    for (int j = 0; j < C_IN / 4; ++j) {
      float4 v = fp[j];
      f[4 * j] = v.x; f[4 * j + 1] = v.y; f[4 * j + 2] = v.z; f[4 * j + 3] = v.w;
    }
  } else {
#pragma unroll
    for (int j = 0; j < C_IN; ++j) f[j] = 0.f;
  }

  float acc[8], accR[8];
#pragma unroll
  for (int j = 0; j < 8; ++j) { acc[j] = 0.f; accR[j] = 0.f; }

  __syncthreads();

  // residual from LDS Win
#pragma unroll
  for (int c = 0; c < C_IN; ++c) {
    const float4 wa = *reinterpret_cast<const float4*>(&sWin[c * C_OUT + d0]);
    const float4 wb = *reinterpret_cast<const float4*>(&sWin[c * C_OUT + d0 + 4]);
    accR[0] = fmaf(f[c], wa.x, accR[0]); accR[1] = fmaf(f[c], wa.y, accR[1]);
    accR[2] = fmaf(f[c], wa.z, accR[2]); accR[3] = fmaf(f[c], wa.w, accR[3]);
    accR[4] = fmaf(f[c], wb.x, accR[4]); accR[5] = fmaf(f[c], wb.y, accR[5]);
    accR[6] = fmaf(f[c], wb.z, accR[6]); accR[7] = fmaf(f[c], wb.w, accR[7]);
  }

  for (int k = 0; k < KK; ++k) {
    uint4 r0, r1;
    if (k + 1 < KK) {
      // issue next gather + stage next weight slice
      int idxn = valid ? nbT[(size_t)(k + 1) * NROWS + row] : 0;
      const uint4* gn = reinterpret_cast<const uint4*>(featb + (size_t)idxn * C_IN);
      r0 = gn[0]; r1 = gn[1];
      if (tid < 128)
        reinterpret_cast<float4*>(sW[(k + 1) & 1])[tid] =
            reinterpret_cast<const float4*>(W1 + (size_t)(k + 1) * C_IN * C_OUT)[tid];
    }
    // compute current k
    const unsigned sel = 0u - ((um >> k) & 1u);
    uint4 p0 = q0, p1 = q1;
    p0.x &= sel; p0.y &= sel; p0.z &= sel; p0.w &= sel;
    p1.x &= sel; p1.y &= sel; p1.z &= sel; p1.w &= sel;
    float g[C_IN];
    g[0] = blo(p0.x);  g[1] = bhi(p0.x);  g[2] = blo(p0.y);  g[3] = bhi(p0.y);
    g[4] = blo(p0.z);  g[5] = bhi(p0.z);  g[6] = blo(p0.w);  g[7] = bhi(p0.w);
    g[8] = blo(p1.x);  g[9] = bhi(p1.x);  g[10] = blo(p1.y); g[11] = bhi(p1.y);
    g[12] = blo(p1.z); g[13] = bhi(p1.z); g[14] = blo(p1.w); g[15] = bhi(p1.w);
    const float* wk = sW[k & 1];
#pragma unroll
    for (int c = 0; c < C_IN; ++c) {
      const float4 wa = *reinterpret_cast<const float4*>(&wk[c * C_OUT + d0]);
      const float4 wb = *reinterpret_cast<const float4*>(&wk[c * C_OUT + d0 + 4]);
      acc[0] = fmaf(g[c], wa.x, acc[0]); acc[1] = fmaf(g[c], wa.y, acc[1]);
      acc[2] = fmaf(g[c], wa.z, acc[2]); acc[3] = fmaf(g[c], wa.w, acc[3]);
      acc[4] = fmaf(g[c], wb.x, acc[4]); acc[5] = fmaf(g[c], wb.y, acc[5]);
      acc[6] = fmaf(g[c], wb.z, acc[6]); acc[7] = fmaf(g[c], wb.w, acc[7]);
    }
    if (k + 1 < KK) { q0 = r0; q1 = r1; }
    __syncthreads();
  }

  if (valid) {
    float4 s0 = make_float4(acc[0], acc[1], acc[2], acc[3]);
    float4 s1 = make_float4(acc[4], acc[5], acc[6], acc[7]);
    reinterpret_cast<float4*>(y1 + (size_t)row * C_OUT + d0)[0] = s0;
    reinterpret_cast<float4*>(y1 + (size_t)row * C_OUT + d0)[1] = s1;
    float4 r0 = make_float4(accR[0], accR[1], accR[2], accR[3]);
    float4 r1 = make_float4(accR[4], accR[5], accR[6], accR[7]);
    reinterpret_cast<float4*>(rbuf + (size_t)row * C_OUT + d0)[0] = r0;
    reinterpret_cast<float4*>(rbuf + (size_t)row * C_OUT + d0)[1] = r1;
  } else {
#pragma unroll
    for (int j = 0; j < 8; ++j) { acc[j] = 0.f; accR[j] = 0.f; }
  }

  // wave-level stats (all 64 lanes share d0; invalid lanes contribute 0)
#pragma unroll
  for (int j = 0; j < 8; ++j) {
    float v = acc[j], s = acc[j] * acc[j];
    float vr = accR[j], sr = accR[j] * accR[j];
#pragma unroll
    for (int m = 32; m >= 1; m >>= 1) {
      v += __shfl_xor(v, m); s += __shfl_xor(s, m);
      vr += __shfl_xor(vr, m); sr += __shfl_xor(sr, m);
    }
    if (lane == 0) {
      atomicAdd(&stats[ST_SUM1 + d0 + j], v);
      atomicAdd(&stats[ST_SQ1 + d0 + j], s);
      atomicAdd(&stats[ST_SUMR + d0 + j], vr);
      atomicAdd(&stats[ST_SQR + d0 + j], sr);
    }
  }
}

// ---------------- bn1: x1b = bf16(lrelu(bn(y1))) ----------------
__global__ __launch_bounds__(256) void k_bn1(
    const float* __restrict__ y1, const float* __restrict__ stats,
    const float* __restrict__ g1, const float* __restrict__ b1,
    u16* __restrict__ x1b) {
  const int i = blockIdx.x * 256 + threadIdx.x;  // 8-float chunk index
  if (i >= NC / 8) return;
  const int d0 = (i * 8) & (C_OUT - 1);
  const float4* yp = reinterpret_cast<const float4*>(y1 + (size_t)i * 8);
  float4 a = yp[0], b = yp[1];
  float vv[8] = {a.x, a.y, a.z, a.w, b.x, b.y, b.z, b.w};
  float o[8];
#pragma unroll
  for (int j = 0; j < 8; ++j) {
    const int d = d0 + j;
    const float mean = stats[ST_SUM1 + d] * (1.0f / NROWS);
    const float var = stats[ST_SQ1 + d] * (1.0f / NROWS) - mean * mean;
    const float inv = 1.0f / sqrtf(var + EPS);
    const float x = (vv[j] - mean) * inv * g1[d] + b1[d];
    o[j] = x >= 0.f ? x : SLOPE * x;
  }
  uint4 r;
  r.x = pack2(o[0], o[1]); r.y = pack2(o[2], o[3]);
  r.z = pack2(o[4], o[5]); r.w = pack2(o[6], o[7]);
  reinterpret_cast<uint4*>(x1b)[i] = r;
}

// ---------------- conv2: LDS-staged weights + pipelined bf16 gathers + stats -------------
__global__ __launch_bounds__(256, 4) void k_conv2(
    const u16* __restrict__ x1b, const int* __restrict__ nbT,
    const unsigned* __restrict__ umask, const float* __restrict__ W2,
    float* __restrict__ y2, float* __restrict__ stats) {
  __shared__ float sW[2][C_OUT * C_OUT];  // 2 x 4 KB double buffer
  const int tid = threadIdx.x;
  const int lane = tid & 63;
  const int d0 = (tid >> 6) * 8;          // wave-uniform
  const int row = blockIdx.x * 64 + lane;
  const bool valid = row < NROWS;
  const unsigned um = valid ? umask[row] : 0u;

  // stage W2[k=0]: 1024 floats = 256 threads x float4
  reinterpret_cast<float4*>(sW[0])[tid] = reinterpret_cast<const float4*>(W2)[tid];

  // prefetch gather for k=0
  int idx0 = valid ? nbT[row] : 0;
  const uint4* g0 = reinterpret_cast<const uint4*>(x1b + (size_t)idx0 * C_OUT);
  uint4 q0 = g0[0], q1 = g0[1], q2 = g0[2], q3 = g0[3];

  float acc[8];
#pragma unroll
  for (int j = 0; j < 8; ++j) acc[j] = 0.f;

  __syncthreads();

  for (int k = 0; k < KK; ++k) {
    uint4 r0, r1, r2, r3;
    if (k + 1 < KK) {
      int idxn = valid ? nbT[(size_t)(k + 1) * NROWS + row] : 0;
      const uint4* gn = reinterpret_cast<const uint4*>(x1b + (size_t)idxn * C_OUT);
      r0 = gn[0]; r1 = gn[1]; r2 = gn[2]; r3 = gn[3];
      reinterpret_cast<float4*>(sW[(k + 1) & 1])[tid] =
          reinterpret_cast<const float4*>(W2 + (size_t)(k + 1) * C_OUT * C_OUT)[tid];
    }
    const unsigned sel = 0u - ((um >> k) & 1u);
    uint4 p0 = q0, p1 = q1, p2 = q2, p3 = q3;
    p0.x &= sel; p0.y &= sel; p0.z &= sel; p0.w &= sel;
    p1.x &= sel; p1.y &= sel; p1.z &= sel; p1.w &= sel;
    p2.x &= sel; p2.y &= sel; p2.z &= sel; p2.w &= sel;
    p3.x &= sel; p3.y &= sel; p3.z &= sel; p3.w &= sel;
    float g[C_OUT];
    g[0] = blo(p0.x);  g[1] = bhi(p0.x);  g[2] = blo(p0.y);  g[3] = bhi(p0.y);
    g[4] = blo(p0.z);  g[5] = bhi(p0.z);  g[6] = blo(p0.w);  g[7] = bhi(p0.w);
    g[8] = blo(p1.x);  g[9] = bhi(p1.x);  g[10] = blo(p1.y); g[11] = bhi(p1.y);
    g[12] = blo(p1.z); g[13] = bhi(p1.z); g[14] = blo(p1.w); g[15] = bhi(p1.w);
    g[16] = blo(p2.x); g[17] = bhi(p2.x); g[18] = blo(p2.y); g[19] = bhi(p2.y);
    g[20] = blo(p2.z); g[21] = bhi(p2.z); g[22] = blo(p2.w); g[23] = bhi(p2.w);
    g[24] = blo(p3.x); g[25] = bhi(p3.x); g[26] = blo(p3.y); g[27] = bhi(p3.y);
    g[28] = blo(p3.z); g[29] = bhi(p3.z); g[30] = blo(p3.w); g[31] = bhi(p3.w);
    const float* wk = sW[k & 1];
#pragma unroll
    for (int c = 0; c < C_OUT; ++c) {
      const float4 wa = *reinterpret_cast<const float4*>(&wk[c * C_OUT + d0]);
      const float4 wb = *reinterpret_cast<const float4*>(&wk[c * C_OUT + d0 + 4]);
      acc[0] = fmaf(g[c], wa.x, acc[0]); acc[1] = fmaf(g[c], wa.y, acc[1]);
      acc[2] = fmaf(g[c], wa.z, acc[2]); acc[3] = fmaf(g[c], wa.w, acc[3]);
      acc[4] = fmaf(g[c], wb.x, acc[4]); acc[5] = fmaf(g[c], wb.y, acc[5]);
      acc[6] = fmaf(g[c], wb.z, acc[6]); acc[7] = fmaf(g[c], wb.w, acc[7]);
    }
    if (k + 1 < KK) { q0 = r0; q1 = r1; q2 = r2; q3 = r3; }
    __syncthreads();
  }

  if (valid) {
    float4 s0 = make_float4(acc[0], acc[1], acc[2], acc[3]);
    float4 s1 = make_float4(acc[4], acc[5], acc[6], acc[7]);
    reinterpret_cast<float4*>(y2 + (size_t)row * C_OUT + d0)[0] = s0;
    reinterpret_cast<float4*>(y2 + (size_t)row * C_OUT + d0)[1] = s1;
  } else {
#pragma unroll
    for (int j = 0; j < 8; ++j) acc[j] = 0.f;
  }

#pragma unroll
  for (int j = 0; j < 8; ++j) {
    float v = acc[j], s = acc[j] * acc[j];
#pragma unroll
    for (int m = 32; m >= 1; m >>= 1) {
      v += __shfl_xor(v, m); s += __shfl_xor(s, m);
    }
    if (lane == 0) {
      atomicAdd(&stats[ST_SUM2 + d0 + j], v);
      atomicAdd(&stats[ST_SQ2 + d0 + j], s);
    }
  }
}

// ---------------- out = lrelu(bn(y2) + bn(r)) ----------------
__global__ __launch_bounds__(256) void k_out(
    const float* __restrict__ y2, const float* __restrict__ rbuf,
    const float* __restrict__ stats,
    const float* __restrict__ g2, const float* __restrict__ b2,
    const float* __restrict__ gin, const float* __restrict__ bin_,
    float* __restrict__ out) {
  const int i = blockIdx.x * 256 + threadIdx.x;  // float4 index
  if (i >= NC / 4) return;
  const int d0 = (i * 4) & (C_OUT - 1);
  float4 v2 = reinterpret_cast<const float4*>(y2)[i];
  float4 vr = reinterpret_cast<const float4*>(rbuf)[i];
  float a2[4] = {v2.x, v2.y, v2.z, v2.w};
  float ar[4] = {vr.x, vr.y, vr.z, vr.w};
  float o[4];
#pragma unroll
  for (int j = 0; j < 4; ++j) {
    const int d = d0 + j;
    const float m2 = stats[ST_SUM2 + d] * (1.0f / NROWS);
    const float va2 = stats[ST_SQ2 + d] * (1.0f / NROWS) - m2 * m2;
    const float i2 = 1.0f / sqrtf(va2 + EPS);
    const float mr = stats[ST_SUMR + d] * (1.0f / NROWS);
    const float var_r = stats[ST_SQR + d] * (1.0f / NROWS) - mr * mr;
    const float ir = 1.0f / sqrtf(var_r + EPS);
    const float xa = (a2[j] - m2) * i2 * g2[d] + b2[d];
    const float xr = (ar[j] - mr) * ir * gin[d] + bin_[d];
    const float s = xa + xr;
    o[j] = s >= 0.f ? s : SLOPE * s;
  }
  reinterpret_cast<float4*>(out)[i] = make_float4(o[0], o[1], o[2], o[3]);
}

extern "C" void kernel_launch(void* const* d_in, const int* in_sizes, int n_in,
                              void* d_out, int out_size, void* d_ws, size_t ws_size,
                              hipStream_t stream) {
  (void)in_sizes; (void)n_in; (void)out_size; (void)ws_size;
  const float* features = (const float*)d_in[0];
  const int* neighbors = (const int*)d_in[1];
  const void* mask = d_in[2];
  const float* W1 = (const float*)d_in[3];
  const float* g1 = (const float*)d_in[4];
  const float* b1 = (const float*)d_in[5];
  const float* W2 = (const float*)d_in[6];
  const float* g2 = (const float*)d_in[7];
  const float* b2 = (const float*)d_in[8];
  const float* Win = (const float*)d_in[9];
  const float* gin = (const float*)d_in[10];
  const float* bin_ = (const float*)d_in[11];
  float* out = (float*)d_out;

  // ws layout (float units):
  // rbuf[NC] | stats[192 pad 256] | umask[NROWS u32] | featb[NROWS*16 u16 = NROWS*8 f]
  // | nbT[KK*NROWS i32] | x1b[NC u16 = NC/2 f]
  float* ws = (float*)d_ws;
  float* rbuf = ws;
  float* stats = ws + (size_t)NC;
  int* flag = (int*)(ws + (size_t)NC + 192);
  unsigned* umask = (unsigned*)(ws + (size_t)NC + 256);
  u16* featb = (u16*)(ws + (size_t)NC + 256 + NROWS);
  int* nbT = (int*)(ws + (size_t)NC + 256 + NROWS + (size_t)NROWS * 8);
  u16* x1b = (u16*)(ws + (size_t)NC + 256 + NROWS + (size_t)NROWS * 8 + (size_t)KK * NROWS);

  hipMemsetAsync(stats, 0, 192 * sizeof(float), stream);

  const int rowBlocks = (NROWS + 255) / 256;      // 391
  const int convBlocks = (NROWS + 63) / 64;       // 1563 (64 rows/block, 4 waves)
  const int bn1Blocks = (NC / 8 + 255) / 256;     // 1563
  const int ewBlocks = (NC / 4 + 255) / 256;      // 3125

  k_detect<<<1, 256, 0, stream>>>((const unsigned char*)mask, flag);
  k_canon<<<rowBlocks, 256, 0, stream>>>(mask, flag, neighbors, features,
                                         umask, featb, nbT);
  k_conv1<<<convBlocks, 256, 0, stream>>>(features, featb, nbT, umask, W1, Win,
                                          out /*y1*/, rbuf, stats);
  k_bn1<<<bn1Blocks, 256, 0, stream>>>(out /*y1*/, stats, g1, b1, x1b);
  k_conv2<<<convBlocks, 256, 0, stream>>>(x1b, nbT, umask, W2, out /*y2*/, stats);
  k_out<<<ewBlocks, 256, 0, stream>>>(out /*y2*/, rbuf, stats, g2, b2, gin, bin_, out);
}

// Round 11
// 961.487 us; speedup vs baseline: 1.5433x; 1.5433x over previous
//
#include <hip/hip_runtime.h>

#define NROWS 100000
#define C_IN 16
#define C_OUT 32
#define KK 27
#define EPS 1e-5f
#define SLOPE 0.01f

#define NC (NROWS * C_OUT)

// stats layout (floats): sum1, sq1, sumR, sqR, sum2, sq2 (32 each)
#define ST_SUM1 0
#define ST_SQ1  32
#define ST_SUMR 64
#define ST_SQR  96
#define ST_SUM2 128
#define ST_SQ2  160

typedef unsigned short u16;

__device__ __forceinline__ unsigned bf16rne(float x) {
  unsigned u = __float_as_uint(x);
  return (u + 0x7fffu + ((u >> 16) & 1u)) >> 16;
}
__device__ __forceinline__ unsigned pack2(float lo, float hi) {
  return bf16rne(lo) | (bf16rne(hi) << 16);
}
__device__ __forceinline__ float blo(unsigned p) { return __uint_as_float(p << 16); }
__device__ __forceinline__ float bhi(unsigned p) { return __uint_as_float(p & 0xffff0000u); }

// ---------------- mask dtype detection: bool(u8) vs int32 ----------------
__global__ __launch_bounds__(256) void k_detect(const unsigned char* __restrict__ mb,
                                                int* __restrict__ flag) {
  __shared__ int found;
  if (threadIdx.x == 0) found = 0;
  __syncthreads();
  int f = 0;
  for (int i = threadIdx.x; i < 4096; i += 256)
    if ((i & 3) != 0 && mb[i] != 0) f = 1;
  if (f) atomicOr(&found, 1);
  __syncthreads();
  if (threadIdx.x == 0) *flag = found;
}

// ---------------- canon: pack mask bits, bf16 feature table, transpose neighbors --------
__global__ __launch_bounds__(256) void k_canon(
    const void* __restrict__ mask, const int* __restrict__ flag,
    const int* __restrict__ neighbors, const float* __restrict__ features,
    unsigned* __restrict__ umask, u16* __restrict__ featb, int* __restrict__ nbT) {
  const int n = blockIdx.x * 256 + threadIdx.x;
  if (n >= NROWS) return;
  unsigned bits = 0;
  if (*flag) {
    const unsigned char* m = (const unsigned char*)mask + (size_t)n * KK;
#pragma unroll
    for (int k = 0; k < KK; ++k) bits |= (unsigned)(m[k] != 0) << k;
  } else {
    const int* m = (const int*)mask + (size_t)n * KK;
#pragma unroll
    for (int k = 0; k < KK; ++k) bits |= (unsigned)(m[k] != 0) << k;
  }
  umask[n] = bits;

  const int* nb = neighbors + (size_t)n * KK;
#pragma unroll
  for (int k = 0; k < KK; ++k) nbT[(size_t)k * NROWS + n] = nb[k];

  const float4* fp = reinterpret_cast<const float4*>(features + (size_t)n * C_IN);
  float f[C_IN];
#pragma unroll
  for (int j = 0; j < C_IN / 4; ++j) {
    float4 v = fp[j];
    f[4 * j] = v.x; f[4 * j + 1] = v.y; f[4 * j + 2] = v.z; f[4 * j + 3] = v.w;
  }
  uint4 r0, r1;
  r0.x = pack2(f[0], f[1]);  r0.y = pack2(f[2], f[3]);
  r0.z = pack2(f[4], f[5]);  r0.w = pack2(f[6], f[7]);
  r1.x = pack2(f[8], f[9]);  r1.y = pack2(f[10], f[11]);
  r1.z = pack2(f[12], f[13]); r1.w = pack2(f[14], f[15]);
  uint4* fb = reinterpret_cast<uint4*>(featb + (size_t)n * C_IN);
  fb[0] = r0; fb[1] = r1;
}

// ---------------- conv1: R=2 rows/thread, LDS dbuf weights, chunked unpack ----------------
// block 256 = 4 waves; wave w: channels [w*8, w*8+8); block rows [bid*128, bid*128+128)
__global__ __launch_bounds__(256, 2) void k_conv1(
    const float* __restrict__ features, const u16* __restrict__ featb,
    const int* __restrict__ nbT, const unsigned* __restrict__ umask,
    const float* __restrict__ W1, const float* __restrict__ Win,
    float* __restrict__ y1, float* __restrict__ rbuf, float* __restrict__ stats) {
  __shared__ float sW[2][C_IN * C_OUT];   // 2 x 2 KB
  __shared__ float sWin[C_IN * C_OUT];    // 2 KB
  const int tid = threadIdx.x;
  const int lane = tid & 63;
  const int d0 = (tid >> 6) * 8;          // wave-uniform
  const int r0 = blockIdx.x * 128 + lane;
  const int r1 = r0 + 64;
  const bool v0 = r0 < NROWS, v1 = r1 < NROWS;
  const int r0c = v0 ? r0 : 0, r1c = v1 ? r1 : 0;
  const unsigned um0 = v0 ? umask[r0] : 0u;
  const unsigned um1 = v1 ? umask[r1] : 0u;

  // stage Win + W1[k=0]
  if (tid < 128) {
    reinterpret_cast<float4*>(sWin)[tid] = reinterpret_cast<const float4*>(Win)[tid];
    reinterpret_cast<float4*>(sW[0])[tid] = reinterpret_cast<const float4*>(W1)[tid];
  }
  __syncthreads();

  // ---- prologue: residual (both rows) + its stats; registers die afterwards ----
  {
    float fa[C_IN], fb[C_IN];
#pragma unroll
    for (int j = 0; j < C_IN / 4; ++j) {
      float4 va = v0 ? reinterpret_cast<const float4*>(features + (size_t)r0 * C_IN)[j]
                     : make_float4(0.f, 0.f, 0.f, 0.f);
      float4 vb = v1 ? reinterpret_cast<const float4*>(features + (size_t)r1 * C_IN)[j]
                     : make_float4(0.f, 0.f, 0.f, 0.f);
      fa[4 * j] = va.x; fa[4 * j + 1] = va.y; fa[4 * j + 2] = va.z; fa[4 * j + 3] = va.w;
      fb[4 * j] = vb.x; fb[4 * j + 1] = vb.y; fb[4 * j + 2] = vb.z; fb[4 * j + 3] = vb.w;
    }
    float ra[8], rb[8];
#pragma unroll
    for (int j = 0; j < 8; ++j) { ra[j] = 0.f; rb[j] = 0.f; }
#pragma unroll
    for (int c = 0; c < C_IN; ++c) {
      const float4 wa = *reinterpret_cast<const float4*>(&sWin[c * C_OUT + d0]);
      const float4 wb = *reinterpret_cast<const float4*>(&sWin[c * C_OUT + d0 + 4]);
      ra[0] = fmaf(fa[c], wa.x, ra[0]); ra[1] = fmaf(fa[c], wa.y, ra[1]);
      ra[2] = fmaf(fa[c], wa.z, ra[2]); ra[3] = fmaf(fa[c], wa.w, ra[3]);
      ra[4] = fmaf(fa[c], wb.x, ra[4]); ra[5] = fmaf(fa[c], wb.y, ra[5]);
      ra[6] = fmaf(fa[c], wb.z, ra[6]); ra[7] = fmaf(fa[c], wb.w, ra[7]);
      rb[0] = fmaf(fb[c], wa.x, rb[0]); rb[1] = fmaf(fb[c], wa.y, rb[1]);
      rb[2] = fmaf(fb[c], wa.z, rb[2]); rb[3] = fmaf(fb[c], wa.w, rb[3]);
      rb[4] = fmaf(fb[c], wb.x, rb[4]); rb[5] = fmaf(fb[c], wb.y, rb[5]);
      rb[6] = fmaf(fb[c], wb.z, rb[6]); rb[7] = fmaf(fb[c], wb.w, rb[7]);
    }
    if (v0) {
      reinterpret_cast<float4*>(rbuf + (size_t)r0 * C_OUT + d0)[0] =
          make_float4(ra[0], ra[1], ra[2], ra[3]);
      reinterpret_cast<float4*>(rbuf + (size_t)r0 * C_OUT + d0)[1] =
          make_float4(ra[4], ra[5], ra[6], ra[7]);
    }
    if (v1) {
      reinterpret_cast<float4*>(rbuf + (size_t)r1 * C_OUT + d0)[0] =
          make_float4(rb[0], rb[1], rb[2], rb[3]);
      reinterpret_cast<float4*>(rbuf + (size_t)r1 * C_OUT + d0)[1] =
          make_float4(rb[4], rb[5], rb[6], rb[7]);
    }
#pragma unroll
    for (int j = 0; j < 8; ++j) {
      float v = ra[j] + rb[j];
      float s = ra[j] * ra[j] + rb[j] * rb[j];
#pragma unroll
      for (int m = 32; m >= 1; m >>= 1) {
        v += __shfl_xor(v, m); s += __shfl_xor(s, m);
      }
      if (lane == 0) {
        atomicAdd(&stats[ST_SUMR + d0 + j], v);
        atomicAdd(&stats[ST_SQR + d0 + j], s);
      }
    }
  }

  // ---- main k-loop ----
  float a0[8], a1[8];
#pragma unroll
  for (int j = 0; j < 8; ++j) { a0[j] = 0.f; a1[j] = 0.f; }

  int ia = nbT[r0c], ib = nbT[r1c];
  for (int k = 0; k < KK; ++k) {
    if (k + 1 < KK && tid < 128)
      reinterpret_cast<float4*>(sW[(k + 1) & 1])[tid] =
          reinterpret_cast<const float4*>(W1 + (size_t)(k + 1) * C_IN * C_OUT)[tid];
    int ian = ia, ibn = ib;
    if (k + 1 < KK) {
      ian = nbT[(size_t)(k + 1) * NROWS + r0c];
      ibn = nbT[(size_t)(k + 1) * NROWS + r1c];
    }
    const uint4* ga = reinterpret_cast<const uint4*>(featb + (size_t)ia * C_IN);
    const uint4* gb = reinterpret_cast<const uint4*>(featb + (size_t)ib * C_IN);
    uint4 pa0 = ga[0], pa1 = ga[1];
    uint4 pb0 = gb[0], pb1 = gb[1];
    const unsigned sa = 0u - ((um0 >> k) & 1u);
    const unsigned sb = 0u - ((um1 >> k) & 1u);
    pa0.x &= sa; pa0.y &= sa; pa0.z &= sa; pa0.w &= sa;
    pa1.x &= sa; pa1.y &= sa; pa1.z &= sa; pa1.w &= sa;
    pb0.x &= sb; pb0.y &= sb; pb0.z &= sb; pb0.w &= sb;
    pb1.x &= sb; pb1.y &= sb; pb1.z &= sb; pb1.w &= sb;
    const float* wk = sW[k & 1];
    // chunk 0: channels 0..7
    {
      float ga_[8] = {blo(pa0.x), bhi(pa0.x), blo(pa0.y), bhi(pa0.y),
                      blo(pa0.z), bhi(pa0.z), blo(pa0.w), bhi(pa0.w)};
      float gb_[8] = {blo(pb0.x), bhi(pb0.x), blo(pb0.y), bhi(pb0.y),
                      blo(pb0.z), bhi(pb0.z), blo(pb0.w), bhi(pb0.w)};
#pragma unroll
      for (int j = 0; j < 8; ++j) {
        const int c = j;
        const float4 wa = *reinterpret_cast<const float4*>(&wk[c * C_OUT + d0]);
        const float4 wb = *reinterpret_cast<const float4*>(&wk[c * C_OUT + d0 + 4]);
        a0[0] = fmaf(ga_[j], wa.x, a0[0]); a0[1] = fmaf(ga_[j], wa.y, a0[1]);
        a0[2] = fmaf(ga_[j], wa.z, a0[2]); a0[3] = fmaf(ga_[j], wa.w, a0[3]);
        a0[4] = fmaf(ga_[j], wb.x, a0[4]); a0[5] = fmaf(ga_[j], wb.y, a0[5]);
        a0[6] = fmaf(ga_[j], wb.z, a0[6]); a0[7] = fmaf(ga_[j], wb.w, a0[7]);
        a1[0] = fmaf(gb_[j], wa.x, a1[0]); a1[1] = fmaf(gb_[j], wa.y, a1[1]);
        a1[2] = fmaf(gb_[j], wa.z, a1[2]); a1[3] = fmaf(gb_[j], wa.w, a1[3]);
        a1[4] = fmaf(gb_[j], wb.x, a1[4]); a1[5] = fmaf(gb_[j], wb.y, a1[5]);
        a1[6] = fmaf(gb_[j], wb.z, a1[6]); a1[7] = fmaf(gb_[j], wb.w, a1[7]);
      }
    }
    // chunk 1: channels 8..15
    {
      float ga_[8] = {blo(pa1.x), bhi(pa1.x), blo(pa1.y), bhi(pa1.y),
                      blo(pa1.z), bhi(pa1.z), blo(pa1.w), bhi(pa1.w)};
      float gb_[8] = {blo(pb1.x), bhi(pb1.x), blo(pb1.y), bhi(pb1.y),
                      blo(pb1.z), bhi(pb1.z), blo(pb1.w), bhi(pb1.w)};
#pragma unroll
      for (int j = 0; j < 8; ++j) {
        const int c = 8 + j;
        const float4 wa = *reinterpret_cast<const float4*>(&wk[c * C_OUT + d0]);
        const float4 wb = *reinterpret_cast<const float4*>(&wk[c * C_OUT + d0 + 4]);
        a0[0] = fmaf(ga_[j], wa.x, a0[0]); a0[1] = fmaf(ga_[j], wa.y, a0[1]);
        a0[2] = fmaf(ga_[j], wa.z, a0[2]); a0[3] = fmaf(ga_[j], wa.w, a0[3]);
        a0[4] = fmaf(ga_[j], wb.x, a0[4]); a0[5] = fmaf(ga_[j], wb.y, a0[5]);
        a0[6] = fmaf(ga_[j], wb.z, a0[6]); a0[7] = fmaf(ga_[j], wb.w, a0[7]);
        a1[0] = fmaf(gb_[j], wa.x, a1[0]); a1[1] = fmaf(gb_[j], wa.y, a1[1]);
        a1[2] = fmaf(gb_[j], wa.z, a1[2]); a1[3] = fmaf(gb_[j], wa.w, a1[3]);
        a1[4] = fmaf(gb_[j], wb.x, a1[4]); a1[5] = fmaf(gb_[j], wb.y, a1[5]);
        a1[6] = fmaf(gb_[j], wb.z, a1[6]); a1[7] = fmaf(gb_[j], wb.w, a1[7]);
      }
    }
    ia = ian; ib = ibn;
    __syncthreads();
  }

  if (v0) {
    reinterpret_cast<float4*>(y1 + (size_t)r0 * C_OUT + d0)[0] =
        make_float4(a0[0], a0[1], a0[2], a0[3]);
    reinterpret_cast<float4*>(y1 + (size_t)r0 * C_OUT + d0)[1] =
        make_float4(a0[4], a0[5], a0[6], a0[7]);
  }
  if (v1) {
    reinterpret_cast<float4*>(y1 + (size_t)r1 * C_OUT + d0)[0] =
        make_float4(a1[0], a1[1], a1[2], a1[3]);
    reinterpret_cast<float4*>(y1 + (size_t)r1 * C_OUT + d0)[1] =
        make_float4(a1[4], a1[5], a1[6], a1[7]);
  }
#pragma unroll
  for (int j = 0; j < 8; ++j) {
    float v = a0[j] + a1[j];
    float s = a0[j] * a0[j] + a1[j] * a1[j];
#pragma unroll
    for (int m = 32; m >= 1; m >>= 1) {
      v += __shfl_xor(v, m); s += __shfl_xor(s, m);
    }
    if (lane == 0) {
      atomicAdd(&stats[ST_SUM1 + d0 + j], v);
      atomicAdd(&stats[ST_SQ1 + d0 + j], s);
    }
  }
}

// ---------------- bn1: x1b = bf16(lrelu(bn(y1))) ----------------
__global__ __launch_bounds__(256) void k_bn1(
    const float* __restrict__ y1, const float* __restrict__ stats,
    const float* __restrict__ g1, const float* __restrict__ b1,
    u16* __restrict__ x1b) {
  const int i = blockIdx.x * 256 + threadIdx.x;
  if (i >= NC / 8) return;
  const int d0 = (i * 8) & (C_OUT - 1);
  const float4* yp = reinterpret_cast<const float4*>(y1 + (size_t)i * 8);
  float4 a = yp[0], b = yp[1];
  float vv[8] = {a.x, a.y, a.z, a.w, b.x, b.y, b.z, b.w};
  float o[8];
#pragma unroll
  for (int j = 0; j < 8; ++j) {
    const int d = d0 + j;
    const float mean = stats[ST_SUM1 + d] * (1.0f / NROWS);
    const float var = stats[ST_SQ1 + d] * (1.0f / NROWS) - mean * mean;
    const float inv = 1.0f / sqrtf(var + EPS);
    const float x = (vv[j] - mean) * inv * g1[d] + b1[d];
    o[j] = x >= 0.f ? x : SLOPE * x;
  }
  uint4 r;
  r.x = pack2(o[0], o[1]); r.y = pack2(o[2], o[3]);
  r.z = pack2(o[4], o[5]); r.w = pack2(o[6], o[7]);
  reinterpret_cast<uint4*>(x1b)[i] = r;
}

// ---------------- conv2: R=2 rows/thread, LDS dbuf weights, chunked unpack ---------------
__global__ __launch_bounds__(256, 2) void k_conv2(
    const u16* __restrict__ x1b, const int* __restrict__ nbT,
    const unsigned* __restrict__ umask, const float* __restrict__ W2,
    float* __restrict__ y2, float* __restrict__ stats) {
  __shared__ float sW[2][C_OUT * C_OUT];  // 2 x 4 KB
  const int tid = threadIdx.x;
  const int lane = tid & 63;
  const int d0 = (tid >> 6) * 8;
  const int r0 = blockIdx.x * 128 + lane;
  const int r1 = r0 + 64;
  const bool v0 = r0 < NROWS, v1 = r1 < NROWS;
  const int r0c = v0 ? r0 : 0, r1c = v1 ? r1 : 0;
  const unsigned um0 = v0 ? umask[r0] : 0u;
  const unsigned um1 = v1 ? umask[r1] : 0u;

  reinterpret_cast<float4*>(sW[0])[tid] = reinterpret_cast<const float4*>(W2)[tid];
  __syncthreads();

  float a0[8], a1[8];
#pragma unroll
  for (int j = 0; j < 8; ++j) { a0[j] = 0.f; a1[j] = 0.f; }

  int ia = nbT[r0c], ib = nbT[r1c];
  for (int k = 0; k < KK; ++k) {
    if (k + 1 < KK)
      reinterpret_cast<float4*>(sW[(k + 1) & 1])[tid] =
          reinterpret_cast<const float4*>(W2 + (size_t)(k + 1) * C_OUT * C_OUT)[tid];
    int ian = ia, ibn = ib;
    if (k + 1 < KK) {
      ian = nbT[(size_t)(k + 1) * NROWS + r0c];
      ibn = nbT[(size_t)(k + 1) * NROWS + r1c];
    }
    const uint4* ga = reinterpret_cast<const uint4*>(x1b + (size_t)ia * C_OUT);
    const uint4* gb = reinterpret_cast<const uint4*>(x1b + (size_t)ib * C_OUT);
    const unsigned sa = 0u - ((um0 >> k) & 1u);
    const unsigned sb = 0u - ((um1 >> k) & 1u);
    const float* wk = sW[k & 1];
#pragma unroll
    for (int cq = 0; cq < 4; ++cq) {
      uint4 pa = ga[cq], pb = gb[cq];
      pa.x &= sa; pa.y &= sa; pa.z &= sa; pa.w &= sa;
      pb.x &= sb; pb.y &= sb; pb.z &= sb; pb.w &= sb;
      float ga_[8] = {blo(pa.x), bhi(pa.x), blo(pa.y), bhi(pa.y),
                      blo(pa.z), bhi(pa.z), blo(pa.w), bhi(pa.w)};
      float gb_[8] = {blo(pb.x), bhi(pb.x), blo(pb.y), bhi(pb.y),
                      blo(pb.z), bhi(pb.z), blo(pb.w), bhi(pb.w)};
#pragma unroll
      for (int j = 0; j < 8; ++j) {
        const int c = cq * 8 + j;
        const float4 wa = *reinterpret_cast<const float4*>(&wk[c * C_OUT + d0]);
        const float4 wb = *reinterpret_cast<const float4*>(&wk[c * C_OUT + d0 + 4]);
        a0[0] = fmaf(ga_[j], wa.x, a0[0]); a0[1] = fmaf(ga_[j], wa.y, a0[1]);
        a0[2] = fmaf(ga_[j], wa.z, a0[2]); a0[3] = fmaf(ga_[j], wa.w, a0[3]);
        a0[4] = fmaf(ga_[j], wb.x, a0[4]); a0[5] = fmaf(ga_[j], wb.y, a0[5]);
        a0[6] = fmaf(ga_[j], wb.z, a0[6]); a0[7] = fmaf(ga_[j], wb.w, a0[7]);
        a1[0] = fmaf(gb_[j], wa.x, a1[0]); a1[1] = fmaf(gb_[j], wa.y, a1[1]);
        a1[2] = fmaf(gb_[j], wa.z, a1[2]); a1[3] = fmaf(gb_[j], wa.w, a1[3]);
        a1[4] = fmaf(gb_[j], wb.x, a1[4]); a1[5] = fmaf(gb_[j], wb.y, a1[5]);
        a1[6] = fmaf(gb_[j], wb.z, a1[6]); a1[7] = fmaf(gb_[j], wb.w, a1[7]);
      }
    }
    ia = ian; ib = ibn;
    __syncthreads();
  }

  if (v0) {
    reinterpret_cast<float4*>(y2 + (size_t)r0 * C_OUT + d0)[0] =
        make_float4(a0[0], a0[1], a0[2], a0[3]);
    reinterpret_cast<float4*>(y2 + (size_t)r0 * C_OUT + d0)[1] =
        make_float4(a0[4], a0[5], a0[6], a0[7]);
  }
  if (v1) {
    reinterpret_cast<float4*>(y2 + (size_t)r1 * C_OUT + d0)[0] =
        make_float4(a1[0], a1[1], a1[2], a1[3]);
    reinterpret_cast<float4*>(y2 + (size_t)r1 * C_OUT + d0)[1] =
        make_float4(a1[4], a1[5], a1[6], a1[7]);
  }
#pragma unroll
  for (int j = 0; j < 8; ++j) {
    float v = a0[j] + a1[j];
    float s = a0[j] * a0[j] + a1[j] * a1[j];
#pragma unroll
    for (int m = 32; m >= 1; m >>= 1) {
      v += __shfl_xor(v, m); s += __shfl_xor(s, m);
    }
    if (lane == 0) {
      atomicAdd(&stats[ST_SUM2 + d0 + j], v);
      atomicAdd(&stats[ST_SQ2 + d0 + j], s);
    }
  }
}

// ---------------- out = lrelu(bn(y2) + bn(r)) ----------------
__global__ __launch_bounds__(256) void k_out(
    const float* __restrict__ y2, const float* __restrict__ rbuf,
    const float* __restrict__ stats,
    const float* __restrict__ g2, const float* __restrict__ b2,
    const float* __restrict__ gin, const float* __restrict__ bin_,
    float* __restrict__ out) {
  const int i = blockIdx.x * 256 + threadIdx.x;
  if (i >= NC / 4) return;
  const int d0 = (i * 4) & (C_OUT - 1);
  float4 v2 = reinterpret_cast<const float4*>(y2)[i];
  float4 vr = reinterpret_cast<const float4*>(rbuf)[i];
  float a2[4] = {v2.x, v2.y, v2.z, v2.w};
  float ar[4] = {vr.x, vr.y, vr.z, vr.w};
  float o[4];
#pragma unroll
  for (int j = 0; j < 4; ++j) {
    const int d = d0 + j;
    const float m2 = stats[ST_SUM2 + d] * (1.0f / NROWS);
    const float va2 = stats[ST_SQ2 + d] * (1.0f / NROWS) - m2 * m2;
    const float i2 = 1.0f / sqrtf(va2 + EPS);
    const float mr = stats[ST_SUMR + d] * (1.0f / NROWS);
    const float var_r = stats[ST_SQR + d] * (1.0f / NROWS) - mr * mr;
    const float ir = 1.0f / sqrtf(var_r + EPS);
    const float xa = (a2[j] - m2) * i2 * g2[d] + b2[d];
    const float xr = (ar[j] - mr) * ir * gin[d] + bin_[d];
    const float s = xa + xr;
    o[j] = s >= 0.f ? s : SLOPE * s;
  }
  reinterpret_cast<float4*>(out)[i] = make_float4(o[0], o[1], o[2], o[3]);
}

extern "C" void kernel_launch(void* const* d_in, const int* in_sizes, int n_in,
                              void* d_out, int out_size, void* d_ws, size_t ws_size,
                              hipStream_t stream) {
  (void)in_sizes; (void)n_in; (void)out_size; (void)ws_size;
  const float* features = (const float*)d_in[0];
  const int* neighbors = (const int*)d_in[1];
  const void* mask = d_in[2];
  const float* W1 = (const float*)d_in[3];
  const float* g1 = (const float*)d_in[4];
  const float* b1 = (const float*)d_in[5];
  const float* W2 = (const float*)d_in[6];
  const float* g2 = (const float*)d_in[7];
  const float* b2 = (const float*)d_in[8];
  const float* Win = (const float*)d_in[9];
  const float* gin = (const float*)d_in[10];
  const float* bin_ = (const float*)d_in[11];
  float* out = (float*)d_out;

  // ws layout (float units):
  // rbuf[NC] | stats[192 pad 256] | umask[NROWS u32] | featb[NROWS*16 u16]
  // | nbT[KK*NROWS i32] | x1b[NC u16]
  float* ws = (float*)d_ws;
  float* rbuf = ws;
  float* stats = ws + (size_t)NC;
  int* flag = (int*)(ws + (size_t)NC + 192);
  unsigned* umask = (unsigned*)(ws + (size_t)NC + 256);
  u16* featb = (u16*)(ws + (size_t)NC + 256 + NROWS);
  int* nbT = (int*)(ws + (size_t)NC + 256 + NROWS + (size_t)NROWS * 8);
  u16* x1b = (u16*)(ws + (size_t)NC + 256 + NROWS + (size_t)NROWS * 8 + (size_t)KK * NROWS);

  hipMemsetAsync(stats, 0, 192 * sizeof(float), stream);

  const int rowBlocks = (NROWS + 255) / 256;      // 391
  const int convBlocks = (NROWS + 127) / 128;     // 782 (128 rows/block, R=2)
  const int bn1Blocks = (NC / 8 + 255) / 256;     // 1563
  const int ewBlocks = (NC / 4 + 255) / 256;      // 3125

  k_detect<<<1, 256, 0, stream>>>((const unsigned char*)mask, flag);
  k_canon<<<rowBlocks, 256, 0, stream>>>(mask, flag, neighbors, features,
                                         umask, featb, nbT);
  k_conv1<<<convBlocks, 256, 0, stream>>>(features, featb, nbT, umask, W1, Win,
                                          out /*y1*/, rbuf, stats);
  k_bn1<<<bn1Blocks, 256, 0, stream>>>(out /*y1*/, stats, g1, b1, x1b);
  k_conv2<<<convBlocks, 256, 0, stream>>>(x1b, nbT, umask, W2, out /*y2*/, stats);
  k_out<<<ewBlocks, 256, 0, stream>>>(out /*y2*/, rbuf, stats, g2, b2, gin, bin_, out);
}